// Round 8
// baseline (190.914 us; speedup 1.0000x reference)
//
#include <hip/hip_runtime.h>
#include <stdint.h>

// MultiHeadAttention: B=2, S=2048, HIDDEN=1024, NH=16, HD=64, causal.
// R21: gemm_qkv 128x128/3-blocks-per-CU -> 64x128/6-blocks-per-CU.
//      Evidence: qkv stall-bound (MfmaUtil 22%, VALU 11%, Occ 26%, HBM 18%);
//      grid 768 = exactly 3/CU so each block's vmcnt(0)+barrier drain stalls
//      its 4 waves with too few independent waves to cover (m114 mechanism).
//      Grid 1536 = 6/CU doubles cross-block TLP; LDS 24KB*6=144<=160KiB.
//      R20 lesson: gemm_out was never ~40us (structural clone changed nothing)
//      -> remainder is harness fill floor + small kernels. R19 lesson: frag-
//      read bank conflicts don't move with swizzle (whole-wave b128 sched).
// MFMA 16x16x32 bf16 layouts (HW-verified):
//   A/B frag: lane holds row[m=lane&15][k=(lane>>4)*8 + j]
//   C/D:      row=(lane>>4)*4+reg, col=lane&15
// Swapped QK^T in attn: mfma(kf,qf) -> C[key][q]; keys 4-aligned per lane.

#define HIDDEN 1024
#define NH 16
#define HD 64
#define BATCH 2
#define SEQ 2048

typedef unsigned short u16;
typedef unsigned int u32;
typedef __attribute__((ext_vector_type(8))) short short8;   // 8 bf16
typedef __attribute__((ext_vector_type(4))) float f32x4;

typedef const __attribute__((address_space(1))) u32 gu32;
typedef __attribute__((address_space(3))) u32 lu32;

__device__ __forceinline__ u16 f2bf(float f) {
    u32 u = __float_as_uint(f);
    return (u16)((u + 0x7FFFu + ((u >> 16) & 1u)) >> 16);   // RNE
}

// ---------------- fused fp32 -> bf16 conversion (x + 4 weights) -----------
__global__ void cvt_all(const float* __restrict__ x, const float* __restrict__ Wq,
                        const float* __restrict__ Wk, const float* __restrict__ Wv,
                        const float* __restrict__ Wo, u16* __restrict__ xb,
                        u16* __restrict__ wqb, u16* __restrict__ wkb,
                        u16* __restrict__ wvb, u16* __restrict__ wob) {
    const int blk = blockIdx.x;
    const float* src; u16* dst; int base;
    if (blk < 2048)      { src = x;  dst = xb;  base = blk; }
    else if (blk < 2560) { src = Wq; dst = wqb; base = blk - 2048; }
    else if (blk < 3072) { src = Wk; dst = wkb; base = blk - 2560; }
    else if (blk < 3584) { src = Wv; dst = wvb; base = blk - 3072; }
    else                 { src = Wo; dst = wob; base = blk - 3584; }
    const int i = base * 256 + threadIdx.x;
    float4 a = ((const float4*)src)[2 * i];
    float4 b = ((const float4*)src)[2 * i + 1];
    union { u16 h[8]; uint4 v; } o;
    o.h[0] = f2bf(a.x); o.h[1] = f2bf(a.y); o.h[2] = f2bf(a.z); o.h[3] = f2bf(a.w);
    o.h[4] = f2bf(b.x); o.h[5] = f2bf(b.y); o.h[6] = f2bf(b.z); o.h[7] = f2bf(b.w);
    ((uint4*)dst)[i] = o.v;
}

// ---- async stage: 16 rows x 32 cols (64 B/row) per call ------------------
// XOR-chunk swizzle on row bits [3:2]: physical chunk c holds logical chunk
// c ^ ((row>>2)&3).
__device__ __forceinline__ void stage16(const u16* __restrict__ G, int grow0,
                                        int k0, u16* lds, int rbase, int lane) {
    const int sr = lane >> 2;
    const int lc = (lane & 3) ^ ((sr >> 2) & 3);
    const u16* g = G + (size_t)(grow0 + rbase + sr) * 1024 + k0 + lc * 8;
    __builtin_amdgcn_global_load_lds((gu32*)g, (lu32*)(lds + rbase * 32), 16, 0, 0);
}

// ---------------- fused QKV projection (R21: 64x128, 6 blocks/CU) ---------
// grid (24, 64). Q/K -> [B,H,S,D] direct; V -> [B,H,D,S] via LDS transpose.
// Wave layout 2Mx2N: wave out 32x64; af[2], bf[4], 8 MFMA/step.
__launch_bounds__(256, 6)
__global__ void gemm_qkv(const u16* __restrict__ A, const u16* __restrict__ Wqb,
                         const u16* __restrict__ Wkb, const u16* __restrict__ Wvb,
                         const float* __restrict__ bq, const float* __restrict__ bk,
                         const float* __restrict__ bv, u16* __restrict__ Qo,
                         u16* __restrict__ Ko, u16* __restrict__ Vo) {
    __shared__ u16 As[2][64 * 32];    // 2 x 4 KB
    __shared__ u16 Bs[2][128 * 32];   // 2 x 8 KB -> 24 KB total
    const int which = blockIdx.x >> 3;
    const int n0 = (blockIdx.x & 7) * 128;
    const int m0 = blockIdx.y * 64;
    const u16* Wt = (which == 0) ? Wqb : (which == 1) ? Wkb : Wvb;
    const float* bias = (which == 0) ? bq : (which == 1) ? bk : bv;
    u16* out = (which == 0) ? Qo : (which == 1) ? Ko : Vo;
    const float oscale = (which == 0) ? 0.18033688011112042f : 1.0f;  // log2e/8
    const int t = threadIdx.x;
    const int lane = t & 63, w = t >> 6, quad = lane >> 4, lm = lane & 15;
    const int wm = (w & 1) * 32, wn = (w >> 1) * 64;

    f32x4 acc[2][4] = {};

    auto stage = [&](int k0, int buf) {
        stage16(A, m0, k0, As[buf], w * 16, lane);
        stage16(Wt, n0, k0, Bs[buf], w * 32, lane);
        stage16(Wt, n0, k0, Bs[buf], w * 32 + 16, lane);
    };

    stage(0, 0);
    __syncthreads();
    for (int k0 = 0; k0 < 1024; k0 += 32) {
        const int cur = (k0 >> 5) & 1;
        if (k0 + 32 < 1024) stage(k0 + 32, cur ^ 1);
        short8 af[2], bf[4];
        const int sw = (quad ^ ((lm >> 2) & 3)) * 8;   // swizzled slot (elems)
#pragma unroll
        for (int mi = 0; mi < 2; mi++)
            af[mi] = *(const short8*)(&As[cur][(wm + mi * 16 + lm) * 32] + sw);
#pragma unroll
        for (int ni = 0; ni < 4; ni++)
            bf[ni] = *(const short8*)(&Bs[cur][(wn + ni * 16 + lm) * 32] + sw);
#pragma unroll
        for (int mi = 0; mi < 2; mi++)
#pragma unroll
            for (int ni = 0; ni < 4; ni++)
                acc[mi][ni] = __builtin_amdgcn_mfma_f32_16x16x32_bf16(
                    af[mi], bf[ni], acc[mi][ni], 0, 0, 0);
        __syncthreads();   // drains vmcnt (next tile landed) + guards buf reuse
    }

    if (which == 2) {
        // V: per-wave LDS transpose (64 d x 32 m, 4 KB) -> coalesced
        // [B,H,D,S] stores. Same-wave write->read, lgkmcnt-ordered.
        u16* Tw = ((w < 2) ? (u16*)As + w * 2048 : (u16*)Bs + (w - 2) * 2048);
#pragma unroll
        for (int ni = 0; ni < 4; ni++) {
            const int n_loc = ni * 16 + lm;            // d (0..63)
            const float bv_ = bias[n0 + wn + n_loc];
#pragma unroll
            for (int mi = 0; mi < 2; mi++)
#pragma unroll
                for (int r = 0; r < 4; r++) {
                    const int m_loc = mi * 16 + quad * 4 + r;   // 0..31
                    Tw[n_loc * 32 + (((m_loc >> 3) ^ (n_loc & 3)) * 8) + (m_loc & 7)] =
                        f2bf(acc[mi][ni][r] + bv_);
                }
        }
        const int hh = (n0 + wn) >> 6;
        const int mg = m0 + wm;             // 32-aligned, never straddles batch
        const int bb = mg >> 11, s0 = mg & 2047;
        u16* outp = out + ((size_t)(bb * NH + hh) * HD) * SEQ;
        const int c = lane & 3;             // logical m-chunk (8 elems)
#pragma unroll
        for (int i = 0; i < 4; i++) {
            const int n_loc = i * 16 + (lane >> 2);   // d
            short8 v = *(const short8*)(Tw + n_loc * 32 + ((c ^ (n_loc & 3)) * 8));
            *(short8*)(outp + (size_t)n_loc * SEQ + s0 + c * 8) = v;
        }
    } else {
#pragma unroll
        for (int ni = 0; ni < 4; ni++) {
            const int n = n0 + wn + ni * 16 + lm;
            const float bv_ = bias[n];
            const int h = n >> 6, d = n & 63;
#pragma unroll
            for (int mi = 0; mi < 2; mi++)
#pragma unroll
                for (int r = 0; r < 4; r++) {
                    const int m = m0 + wm + mi * 16 + quad * 4 + r;
                    const int b = m >> 11, s = m & 2047;
                    out[(((size_t)(b * NH + h) * SEQ + s) * HD) + d] =
                        f2bf((acc[mi][ni][r] + bv_) * oscale);
                }
        }
    }
}

// ---------------- output projection (R20: 128x128 / 512 thr / 8 waves) ----
// grid (8, 32) = 256 blocks = 1/CU even. Wave grid 2Mx4N, wave out 64x32.
__launch_bounds__(512, 2)
__global__ void gemm_out(const u16* __restrict__ A, const u16* __restrict__ Wt,
                         const float* __restrict__ bias, float* __restrict__ out) {
    __shared__ u16 As[2][128 * 32];   // 2 x 8 KB
    __shared__ u16 Bs[2][128 * 32];   // 2 x 8 KB -> 32 KB total
    const int n0 = blockIdx.x * 128;
    const int m0 = blockIdx.y * 128;
    const int t = threadIdx.x;
    const int lane = t & 63, w = t >> 6, quad = lane >> 4, lm = lane & 15;
    const int wm = (w & 1) * 64, wn = (w >> 1) * 32;

    f32x4 acc[4][2] = {};

    auto stage = [&](int k0, int buf) {
        stage16(A, m0, k0, As[buf], w * 16, lane);
        stage16(Wt, n0, k0, Bs[buf], w * 16, lane);
    };

    stage(0, 0);
    __syncthreads();
    for (int k0 = 0; k0 < 1024; k0 += 32) {
        const int cur = (k0 >> 5) & 1;
        if (k0 + 32 < 1024) stage(k0 + 32, cur ^ 1);
        short8 af[4], bf[2];
        const int sw = (quad ^ ((lm >> 2) & 3)) * 8;
#pragma unroll
        for (int mi = 0; mi < 4; mi++)
            af[mi] = *(const short8*)(&As[cur][(wm + mi * 16 + lm) * 32] + sw);
#pragma unroll
        for (int ni = 0; ni < 2; ni++)
            bf[ni] = *(const short8*)(&Bs[cur][(wn + ni * 16 + lm) * 32] + sw);
#pragma unroll
        for (int mi = 0; mi < 4; mi++)
#pragma unroll
            for (int ni = 0; ni < 2; ni++)
                acc[mi][ni] = __builtin_amdgcn_mfma_f32_16x16x32_bf16(
                    af[mi], bf[ni], acc[mi][ni], 0, 0, 0);
        __syncthreads();
    }

#pragma unroll
    for (int ni = 0; ni < 2; ni++) {
        const int n = n0 + wn + ni * 16 + lm;
        const float bv_ = bias[n];
#pragma unroll
        for (int mi = 0; mi < 4; mi++)
#pragma unroll
            for (int r = 0; r < 4; r++) {
                const int m = m0 + wm + mi * 16 + quad * 4 + r;
                out[(size_t)m * 1024 + n] = acc[mi][ni][r] + bv_;
            }
    }
}

// ---------------- flash attention, causal (R18, unchanged) ----------------
// Grid 1024 blocks, 256 thr = 4 waves; wave owns 16 q-rows; Q-tile 64,
// K-tile 64, double-buffered via global_load_lds; balanced 66-step/CU map.
// Software-pipelined: QK(kt+1) hides P-write->P-read latency of step kt.
// P row = 16 8B slots, physical slot = l^lm -> conflict-free b64 write+read.
__launch_bounds__(256, 4)
__global__ void attn_kernel(const u16* __restrict__ Q, const u16* __restrict__ K,
                            const u16* __restrict__ Vt, u16* __restrict__ Out) {
    __shared__ u16 Ks[2][64 * 64];    // 2 x 8 KB, swizzled
    __shared__ u16 Vs[2][64 * 64];    // 2 x 8 KB, swizzled
    __shared__ u16 Ps[4 * 16 * 64];   // 8 KB, slot-XOR layout -> 40960 B total
    const int t = threadIdx.x;
    const int lane = t & 63, w = t >> 6, quad = lane >> 4, lm = lane & 15;
    // balanced static schedule: CU c's 4 resident blocks sum to 66 steps
    const int i = blockIdx.x >> 5;
    const int qt = (i < 16) ? (31 - i) : (i - 16);
    const int bh = blockIdx.x & 31;
    const int b = bh >> 4, h = bh & 15;
    const size_t base = (size_t)(b * NH + h) * SEQ * HD;
    const u16* Qg = Q + base;
    const u16* Kg = K + base;
    const u16* Vg = Vt + base;
    const int q0 = qt * 64 + w * 16;
    const int nk = qt + 1;   // number of 64-key steps

    u16* Pw = Ps + w * 16 * 64;

    const int srow = (lane >> 3);          // 0..7 within 8-row group
    const int schunk = (lane & 7) ^ srow;  // source logical chunk (r&7 == srow)
    auto stage_k = [&](int kt, int buf) {
#pragma unroll
        for (int j = 0; j < 2; j++) {
            const int row = w * 16 + j * 8 + srow;
            const u16* gk = Kg + (size_t)(kt * 64 + row) * HD + schunk * 8;
            __builtin_amdgcn_global_load_lds((gu32*)gk, (lu32*)(&Ks[buf][(w * 16 + j * 8) * 64]), 16, 0, 0);
        }
    };
    auto stage_v = [&](int kt, int buf) {
#pragma unroll
        for (int j = 0; j < 2; j++) {
            const int row = w * 16 + j * 8 + srow;
            const u16* gv = Vg + (size_t)row * SEQ + kt * 64 + schunk * 8;
            __builtin_amdgcn_global_load_lds((gu32*)gv, (lu32*)(&Vs[buf][(w * 16 + j * 8) * 64]), 16, 0, 0);
        }
    };

    short8 qf[2];
#pragma unroll
    for (int kk = 0; kk < 2; kk++)
        qf[kk] = *(const short8*)(Qg + (size_t)(q0 + lm) * HD + kk * 32 + quad * 8);

    f32x4 oacc[4] = {};
    f32x4 lacc = {};
    f32x4 sacc[4];
    short8 ones;
#pragma unroll
    for (int j = 0; j < 8; j++) ones[j] = (short)0x3F80;   // bf16 1.0

    // swapped QK^T: sacc[n] = C[key][q], key = n*16+quad*4+reg, q = lm
    auto qk_tile = [&](const u16* Kc) {
        __builtin_amdgcn_s_setprio(1);
#pragma unroll
        for (int n = 0; n < 4; n++) {
            const int r = n * 16 + lm;
            const u16* rowp = Kc + r * 64;
            short8 kf0 = *(const short8*)(rowp + ((quad ^ (r & 7)) * 8));
            short8 kf1 = *(const short8*)(rowp + (((quad + 4) ^ (r & 7)) * 8));
            f32x4 a = {};
            a = __builtin_amdgcn_mfma_f32_16x16x32_bf16(kf0, qf[0], a, 0, 0, 0);
            a = __builtin_amdgcn_mfma_f32_16x16x32_bf16(kf1, qf[1], a, 0, 0, 0);
            sacc[n] = a;
        }
        __builtin_amdgcn_s_setprio(0);
    };

    // prologue: K0 -> Ks[0]; issue K1,V0; QK(0)
    stage_k(0, 0);
    __syncthreads();
    if (nk > 1) stage_k(1, 1);
    stage_v(0, 0);
    qk_tile(Ks[0]);
    __syncthreads();

    for (int kt = 0; kt < nk; kt++) {
        const int kb = kt & 1;
        if (kt + 2 < nk) stage_k(kt + 2, kb);
        if (kt + 1 < nk) stage_v(kt + 1, kb ^ 1);

        // mask (diagonal step only) + exp2 + pack + P-write
        if (kt == qt) {
#pragma unroll
            for (int n = 0; n < 4; n++)
#pragma unroll
                for (int r = 0; r < 4; r++)
                    if (n * 16 + quad * 4 + r > w * 16 + lm)
                        sacc[n][r] = -__builtin_inff();
        }
#pragma unroll
        for (int n = 0; n < 4; n++) {
            float e0 = exp2f(sacc[n][0]), e1 = exp2f(sacc[n][1]);
            float e2 = exp2f(sacc[n][2]), e3 = exp2f(sacc[n][3]);
            u32 lo, hi;
            asm("v_cvt_pk_bf16_f32 %0, %1, %2" : "=v"(lo) : "v"(e0), "v"(e1));
            asm("v_cvt_pk_bf16_f32 %0, %1, %2" : "=v"(hi) : "v"(e2), "v"(e3));
            const int pslot = (n * 4 + quad) ^ lm;     // 8B slot, conflict-free
            *(uint2*)(Pw + lm * 64 + pslot * 4) = (uint2){lo, hi};
        }
        // pf read: logical slots l0, l0+1 -> physical l^lm (b64 pair)
        short8 pf[2];
#pragma unroll
        for (int k4 = 0; k4 < 2; k4++) {
            const int l0 = k4 * 8 + quad * 2;
            uint2 a = *(const uint2*)(Pw + lm * 64 + ((l0 ^ lm) * 4));
            uint2 c = *(const uint2*)(Pw + lm * 64 + (((l0 + 1) ^ lm) * 4));
            union { short8 s; uint4 u; } m_;
            m_.u = (uint4){a.x, a.y, c.x, c.y};
            pf[k4] = m_.s;
        }
        // QK for NEXT tile (independent) -- hides the P LDS round-trip
        if (kt + 1 < nk) qk_tile(Ks[kb ^ 1]);
        // PV + row-sum
        __builtin_amdgcn_s_setprio(1);
#pragma unroll
        for (int n = 0; n < 4; n++) {
            const int r = n * 16 + lm;
            const u16* rowp = Vs[kb] + r * 64;
#pragma unroll
            for (int k4 = 0; k4 < 2; k4++) {
                short8 vf = *(const short8*)(rowp + (((k4 * 4 + quad) ^ (r & 7)) * 8));
                oacc[n] = __builtin_amdgcn_mfma_f32_16x16x32_bf16(pf[k4], vf, oacc[n], 0, 0, 0);
            }
        }
#pragma unroll
        for (int k4 = 0; k4 < 2; k4++)
            lacc = __builtin_amdgcn_mfma_f32_16x16x32_bf16(pf[k4], ones, lacc, 0, 0, 0);
        __builtin_amdgcn_s_setprio(0);

        if (kt + 1 < nk) __syncthreads();   // staged tiles landed; bufs safe
    }

    float inv[4];
#pragma unroll
    for (int r = 0; r < 4; r++) inv[r] = 1.0f / lacc[r];
#pragma unroll
    for (int n = 0; n < 4; n++)
#pragma unroll
        for (int r = 0; r < 4; r++) {
            const int qq = q0 + quad * 4 + r;
            Out[(size_t)(b * SEQ + qq) * HIDDEN + h * HD + n * 16 + lm] =
                f2bf(oacc[n][r] * inv[r]);
        }
}

// ---------------- launcher ------------------------------------------------
extern "C" void kernel_launch(void* const* d_in, const int* in_sizes, int n_in,
                              void* d_out, int out_size, void* d_ws, size_t ws_size,
                              hipStream_t stream) {
    const float* x  = (const float*)d_in[0];
    const float* Wq = (const float*)d_in[1];
    const float* bq = (const float*)d_in[2];
    const float* Wk = (const float*)d_in[3];
    const float* bk = (const float*)d_in[4];
    const float* Wv = (const float*)d_in[5];
    const float* bv = (const float*)d_in[6];
    const float* Wo = (const float*)d_in[7];
    const float* bo = (const float*)d_in[8];
    float* out = (float*)d_out;

    char* ws = (char*)d_ws;
    const size_t SZ_X = (size_t)4096 * 1024 * 2;   // 8 MB bf16
    const size_t SZ_W = (size_t)1024 * 1024 * 2;   // 2 MB bf16
    u16* xb    = (u16*)(ws);
    u16* wqb   = (u16*)(ws + SZ_X);
    u16* wkb   = (u16*)(ws + SZ_X + SZ_W);
    u16* wvb   = (u16*)(ws + SZ_X + 2 * SZ_W);
    u16* wob   = (u16*)(ws + SZ_X + 3 * SZ_W);
    u16* Qb    = (u16*)(ws + SZ_X + 4 * SZ_W);
    u16* Kb    = (u16*)(ws + 2 * SZ_X + 4 * SZ_W);
    u16* Vtb   = (u16*)(ws + 3 * SZ_X + 4 * SZ_W);
    u16* attnb = (u16*)(ws + 4 * SZ_X + 4 * SZ_W);

    cvt_all<<<4096, 256, 0, stream>>>(x, Wq, Wk, Wv, Wo, xb, wqb, wkb, wvb, wob);
    gemm_qkv<<<dim3(24, 64), 256, 0, stream>>>(xb, wqb, wkb, wvb, bq, bk, bv, Qb, Kb, Vtb);
    attn_kernel<<<BATCH * NH * (SEQ / 64), 256, 0, stream>>>(Qb, Kb, Vtb, attnb);
    gemm_out<<<dim3(8, 32), 512, 0, stream>>>(attnb, wob, bo, out);
}

// Round 9
// 181.765 us; speedup vs baseline: 1.0503x; 1.0503x over previous
//
#include <hip/hip_runtime.h>
#include <stdint.h>

// MultiHeadAttention: B=2, S=2048, HIDDEN=1024, NH=16, HD=64, causal.
// R22: gemm_qkv reverted to R20 shape (128x128, 4 waves, 3 blocks/CU --
//      R21's 6/CU refuted: occ 52% but SLOWER) + counted-vmcnt pipeline:
//      3 LDS buffers, stage 2-ahead, s_waitcnt vmcnt(4) at loop bottom
//      (waits tile t+1's 4 oldest loads; tile t+2's 4 stay in flight
//      ACROSS the raw s_barrier -- T4/AITER pattern, never vmcnt(0) in
//      steady state). Diagnosis: MfmaUtil 22% = 9.4us MFMA vs 10.3 ideal;
//      ~70% of kernel was the per-step vmcnt(0) drain in __syncthreads.
//      R19: frag-read conflicts don't move with swizzle. R20: gemm_out
//      was never large. R21: TLP doesn't cover the drain.
// MFMA 16x16x32 bf16 layouts (HW-verified):
//   A/B frag: lane holds row[m=lane&15][k=(lane>>4)*8 + j]
//   C/D:      row=(lane>>4)*4+reg, col=lane&15
// Swapped QK^T in attn: mfma(kf,qf) -> C[key][q]; keys 4-aligned per lane.

#define HIDDEN 1024
#define NH 16
#define HD 64
#define BATCH 2
#define SEQ 2048

typedef unsigned short u16;
typedef unsigned int u32;
typedef __attribute__((ext_vector_type(8))) short short8;   // 8 bf16
typedef __attribute__((ext_vector_type(4))) float f32x4;

typedef const __attribute__((address_space(1))) u32 gu32;
typedef __attribute__((address_space(3))) u32 lu32;

__device__ __forceinline__ u16 f2bf(float f) {
    u32 u = __float_as_uint(f);
    return (u16)((u + 0x7FFFu + ((u >> 16) & 1u)) >> 16);   // RNE
}

// ---------------- fused fp32 -> bf16 conversion (x + 4 weights) -----------
__global__ void cvt_all(const float* __restrict__ x, const float* __restrict__ Wq,
                        const float* __restrict__ Wk, const float* __restrict__ Wv,
                        const float* __restrict__ Wo, u16* __restrict__ xb,
                        u16* __restrict__ wqb, u16* __restrict__ wkb,
                        u16* __restrict__ wvb, u16* __restrict__ wob) {
    const int blk = blockIdx.x;
    const float* src; u16* dst; int base;
    if (blk < 2048)      { src = x;  dst = xb;  base = blk; }
    else if (blk < 2560) { src = Wq; dst = wqb; base = blk - 2048; }
    else if (blk < 3072) { src = Wk; dst = wkb; base = blk - 2560; }
    else if (blk < 3584) { src = Wv; dst = wvb; base = blk - 3072; }
    else                 { src = Wo; dst = wob; base = blk - 3584; }
    const int i = base * 256 + threadIdx.x;
    float4 a = ((const float4*)src)[2 * i];
    float4 b = ((const float4*)src)[2 * i + 1];
    union { u16 h[8]; uint4 v; } o;
    o.h[0] = f2bf(a.x); o.h[1] = f2bf(a.y); o.h[2] = f2bf(a.z); o.h[3] = f2bf(a.w);
    o.h[4] = f2bf(b.x); o.h[5] = f2bf(b.y); o.h[6] = f2bf(b.z); o.h[7] = f2bf(b.w);
    ((uint4*)dst)[i] = o.v;
}

// ---- async stage: 16 rows x 32 cols (64 B/row) per call ------------------
// XOR-chunk swizzle on row bits [3:2]: physical chunk c holds logical chunk
// c ^ ((row>>2)&3).
__device__ __forceinline__ void stage16(const u16* __restrict__ G, int grow0,
                                        int k0, u16* lds, int rbase, int lane) {
    const int sr = lane >> 2;
    const int lc = (lane & 3) ^ ((sr >> 2) & 3);
    const u16* g = G + (size_t)(grow0 + rbase + sr) * 1024 + k0 + lc * 8;
    __builtin_amdgcn_global_load_lds((gu32*)g, (lu32*)(lds + rbase * 32), 16, 0, 0);
}

// ---------------- fused QKV projection (R22) ------------------------------
// grid (24, 32), 128x128, 4 waves (2Mx2N, wave out 64x64), 3 blocks/CU.
// 3-buffer counted-vmcnt pipeline: stage 2-ahead, vmcnt(4) at bottom.
__launch_bounds__(256, 3)
__global__ void gemm_qkv(const u16* __restrict__ A, const u16* __restrict__ Wqb,
                         const u16* __restrict__ Wkb, const u16* __restrict__ Wvb,
                         const float* __restrict__ bq, const float* __restrict__ bk,
                         const float* __restrict__ bv, u16* __restrict__ Qo,
                         u16* __restrict__ Ko, u16* __restrict__ Vo) {
    __shared__ u16 As[3][128 * 32];   // 3 x 8 KB
    __shared__ u16 Bs[3][128 * 32];   // 3 x 8 KB -> 48 KB total
    const int which = blockIdx.x >> 3;
    const int n0 = (blockIdx.x & 7) * 128;
    const int m0 = blockIdx.y * 128;
    const u16* Wt = (which == 0) ? Wqb : (which == 1) ? Wkb : Wvb;
    const float* bias = (which == 0) ? bq : (which == 1) ? bk : bv;
    u16* out = (which == 0) ? Qo : (which == 1) ? Ko : Vo;
    const float oscale = (which == 0) ? 0.18033688011112042f : 1.0f;  // log2e/8
    const int t = threadIdx.x;
    const int lane = t & 63, w = t >> 6, quad = lane >> 4, lm = lane & 15;
    const int wm = (w & 1) * 64, wn = (w >> 1) * 64;

    f32x4 acc[4][4] = {};

    auto stage = [&](int k0, int buf) {     // 4 global_load_lds per thread
        stage16(A, m0, k0, As[buf], w * 32, lane);
        stage16(A, m0, k0, As[buf], w * 32 + 16, lane);
        stage16(Wt, n0, k0, Bs[buf], w * 32, lane);
        stage16(Wt, n0, k0, Bs[buf], w * 32 + 16, lane);
    };

    // prologue: tiles 0,1 in flight (8 loads); wait tile0 (4 oldest)
    stage(0, 0);
    stage(32, 1);
    asm volatile("s_waitcnt vmcnt(4)" ::: "memory");
    __builtin_amdgcn_s_barrier();
    __builtin_amdgcn_sched_barrier(0);

    for (int kt = 0; kt < 32; kt++) {
        const int cur = kt % 3;
        if (kt + 2 < 32) stage((kt + 2) * 32, (kt + 2) % 3);   // 2-ahead
        short8 af[4], bf[4];
        const int sw = (quad ^ ((lm >> 2) & 3)) * 8;   // swizzled slot (elems)
#pragma unroll
        for (int mi = 0; mi < 4; mi++)
            af[mi] = *(const short8*)(&As[cur][(wm + mi * 16 + lm) * 32] + sw);
#pragma unroll
        for (int ni = 0; ni < 4; ni++)
            bf[ni] = *(const short8*)(&Bs[cur][(wn + ni * 16 + lm) * 32] + sw);
#pragma unroll
        for (int mi = 0; mi < 4; mi++)
#pragma unroll
            for (int ni = 0; ni < 4; ni++)
                acc[mi][ni] = __builtin_amdgcn_mfma_f32_16x16x32_bf16(
                    af[mi], bf[ni], acc[mi][ni], 0, 0, 0);
        // wait ONLY for tile kt+1 (4 oldest); kt+2's 4 stay in flight
        if (kt + 2 < 32) asm volatile("s_waitcnt vmcnt(4)" ::: "memory");
        else             asm volatile("s_waitcnt vmcnt(0)" ::: "memory");
        __builtin_amdgcn_s_barrier();
        __builtin_amdgcn_sched_barrier(0);
    }

    if (which == 2) {
        __syncthreads();   // all frag reads done before Tw scribbles LDS
        // V: per-wave LDS transpose -> coalesced [B,H,D,S] stores.
        u16* Tw = ((w < 2) ? (u16*)As : (u16*)Bs) + (w & 1) * 4096;
#pragma unroll
        for (int ni = 0; ni < 4; ni++) {
            const int n_loc = ni * 16 + lm;
            const float bv_ = bias[n0 + wn + n_loc];
#pragma unroll
            for (int mi = 0; mi < 4; mi++)
#pragma unroll
                for (int r = 0; r < 4; r++) {
                    const int m_loc = mi * 16 + quad * 4 + r;
                    Tw[n_loc * 64 + (((m_loc >> 3) ^ (n_loc & 7)) * 8) + (m_loc & 7)] =
                        f2bf(acc[mi][ni][r] + bv_);
                }
        }
        const int hh = (n0 + wn) >> 6;
        const int mg = m0 + wm;             // 64-aligned, never straddles batch
        const int bb = mg >> 11, s0 = mg & 2047;
        u16* outp = out + ((size_t)(bb * NH + hh) * HD) * SEQ;
        const int cm = lane & 7;            // logical m-chunk (8 elems)
#pragma unroll
        for (int i = 0; i < 8; i++) {
            const int n_loc = i * 8 + (lane >> 3);   // d
            short8 v = *(const short8*)(Tw + n_loc * 64 + ((cm ^ (n_loc & 7)) * 8));
            *(short8*)(outp + (size_t)n_loc * SEQ + s0 + cm * 8) = v;
        }
    } else {
#pragma unroll
        for (int ni = 0; ni < 4; ni++) {
            const int n = n0 + wn + ni * 16 + lm;
            const float bv_ = bias[n];
            const int h = n >> 6, d = n & 63;
#pragma unroll
            for (int mi = 0; mi < 4; mi++)
#pragma unroll
                for (int r = 0; r < 4; r++) {
                    const int m = m0 + wm + mi * 16 + quad * 4 + r;
                    const int b = m >> 11, s = m & 2047;
                    out[(((size_t)(b * NH + h) * SEQ + s) * HD) + d] =
                        f2bf((acc[mi][ni][r] + bv_) * oscale);
                }
        }
    }
}

// ---------------- output projection (R20: 128x128 / 512 thr / 8 waves) ----
// grid (8, 32) = 256 blocks = 1/CU even. Wave grid 2Mx4N, wave out 64x32.
__launch_bounds__(512, 2)
__global__ void gemm_out(const u16* __restrict__ A, const u16* __restrict__ Wt,
                         const float* __restrict__ bias, float* __restrict__ out) {
    __shared__ u16 As[2][128 * 32];   // 2 x 8 KB
    __shared__ u16 Bs[2][128 * 32];   // 2 x 8 KB -> 32 KB total
    const int n0 = blockIdx.x * 128;
    const int m0 = blockIdx.y * 128;
    const int t = threadIdx.x;
    const int lane = t & 63, w = t >> 6, quad = lane >> 4, lm = lane & 15;
    const int wm = (w & 1) * 64, wn = (w >> 1) * 32;

    f32x4 acc[4][2] = {};

    auto stage = [&](int k0, int buf) {
        stage16(A, m0, k0, As[buf], w * 16, lane);
        stage16(Wt, n0, k0, Bs[buf], w * 16, lane);
    };

    stage(0, 0);
    __syncthreads();
    for (int k0 = 0; k0 < 1024; k0 += 32) {
        const int cur = (k0 >> 5) & 1;
        if (k0 + 32 < 1024) stage(k0 + 32, cur ^ 1);
        short8 af[4], bf[2];
        const int sw = (quad ^ ((lm >> 2) & 3)) * 8;
#pragma unroll
        for (int mi = 0; mi < 4; mi++)
            af[mi] = *(const short8*)(&As[cur][(wm + mi * 16 + lm) * 32] + sw);
#pragma unroll
        for (int ni = 0; ni < 2; ni++)
            bf[ni] = *(const short8*)(&Bs[cur][(wn + ni * 16 + lm) * 32] + sw);
#pragma unroll
        for (int mi = 0; mi < 4; mi++)
#pragma unroll
            for (int ni = 0; ni < 2; ni++)
                acc[mi][ni] = __builtin_amdgcn_mfma_f32_16x16x32_bf16(
                    af[mi], bf[ni], acc[mi][ni], 0, 0, 0);
        __syncthreads();
    }

#pragma unroll
    for (int ni = 0; ni < 2; ni++) {
        const int n = n0 + wn + ni * 16 + lm;
        const float bv_ = bias[n];
#pragma unroll
        for (int mi = 0; mi < 4; mi++)
#pragma unroll
            for (int r = 0; r < 4; r++) {
                const int m = m0 + wm + mi * 16 + quad * 4 + r;
                out[(size_t)m * 1024 + n] = acc[mi][ni][r] + bv_;
            }
    }
}

// ---------------- flash attention, causal (R18, unchanged) ----------------
// Grid 1024 blocks, 256 thr = 4 waves; wave owns 16 q-rows; Q-tile 64,
// K-tile 64, double-buffered via global_load_lds; balanced 66-step/CU map.
// Software-pipelined: QK(kt+1) hides P-write->P-read latency of step kt.
// P row = 16 8B slots, physical slot = l^lm -> conflict-free b64 write+read.
__launch_bounds__(256, 4)
__global__ void attn_kernel(const u16* __restrict__ Q, const u16* __restrict__ K,
                            const u16* __restrict__ Vt, u16* __restrict__ Out) {
    __shared__ u16 Ks[2][64 * 64];    // 2 x 8 KB, swizzled
    __shared__ u16 Vs[2][64 * 64];    // 2 x 8 KB, swizzled
    __shared__ u16 Ps[4 * 16 * 64];   // 8 KB, slot-XOR layout -> 40960 B total
    const int t = threadIdx.x;
    const int lane = t & 63, w = t >> 6, quad = lane >> 4, lm = lane & 15;
    // balanced static schedule: CU c's 4 resident blocks sum to 66 steps
    const int i = blockIdx.x >> 5;
    const int qt = (i < 16) ? (31 - i) : (i - 16);
    const int bh = blockIdx.x & 31;
    const int b = bh >> 4, h = bh & 15;
    const size_t base = (size_t)(b * NH + h) * SEQ * HD;
    const u16* Qg = Q + base;
    const u16* Kg = K + base;
    const u16* Vg = Vt + base;
    const int q0 = qt * 64 + w * 16;
    const int nk = qt + 1;   // number of 64-key steps

    u16* Pw = Ps + w * 16 * 64;

    const int srow = (lane >> 3);          // 0..7 within 8-row group
    const int schunk = (lane & 7) ^ srow;  // source logical chunk (r&7 == srow)
    auto stage_k = [&](int kt, int buf) {
#pragma unroll
        for (int j = 0; j < 2; j++) {
            const int row = w * 16 + j * 8 + srow;
            const u16* gk = Kg + (size_t)(kt * 64 + row) * HD + schunk * 8;
            __builtin_amdgcn_global_load_lds((gu32*)gk, (lu32*)(&Ks[buf][(w * 16 + j * 8) * 64]), 16, 0, 0);
        }
    };
    auto stage_v = [&](int kt, int buf) {
#pragma unroll
        for (int j = 0; j < 2; j++) {
            const int row = w * 16 + j * 8 + srow;
            const u16* gv = Vg + (size_t)row * SEQ + kt * 64 + schunk * 8;
            __builtin_amdgcn_global_load_lds((gu32*)gv, (lu32*)(&Vs[buf][(w * 16 + j * 8) * 64]), 16, 0, 0);
        }
    };

    short8 qf[2];
#pragma unroll
    for (int kk = 0; kk < 2; kk++)
        qf[kk] = *(const short8*)(Qg + (size_t)(q0 + lm) * HD + kk * 32 + quad * 8);

    f32x4 oacc[4] = {};
    f32x4 lacc = {};
    f32x4 sacc[4];
    short8 ones;
#pragma unroll
    for (int j = 0; j < 8; j++) ones[j] = (short)0x3F80;   // bf16 1.0

    // swapped QK^T: sacc[n] = C[key][q], key = n*16+quad*4+reg, q = lm
    auto qk_tile = [&](const u16* Kc) {
        __builtin_amdgcn_s_setprio(1);
#pragma unroll
        for (int n = 0; n < 4; n++) {
            const int r = n * 16 + lm;
            const u16* rowp = Kc + r * 64;
            short8 kf0 = *(const short8*)(rowp + ((quad ^ (r & 7)) * 8));
            short8 kf1 = *(const short8*)(rowp + (((quad + 4) ^ (r & 7)) * 8));
            f32x4 a = {};
            a = __builtin_amdgcn_mfma_f32_16x16x32_bf16(kf0, qf[0], a, 0, 0, 0);
            a = __builtin_amdgcn_mfma_f32_16x16x32_bf16(kf1, qf[1], a, 0, 0, 0);
            sacc[n] = a;
        }
        __builtin_amdgcn_s_setprio(0);
    };

    // prologue: K0 -> Ks[0]; issue K1,V0; QK(0)
    stage_k(0, 0);
    __syncthreads();
    if (nk > 1) stage_k(1, 1);
    stage_v(0, 0);
    qk_tile(Ks[0]);
    __syncthreads();

    for (int kt = 0; kt < nk; kt++) {
        const int kb = kt & 1;
        if (kt + 2 < nk) stage_k(kt + 2, kb);
        if (kt + 1 < nk) stage_v(kt + 1, kb ^ 1);

        // mask (diagonal step only) + exp2 + pack + P-write
        if (kt == qt) {
#pragma unroll
            for (int n = 0; n < 4; n++)
#pragma unroll
                for (int r = 0; r < 4; r++)
                    if (n * 16 + quad * 4 + r > w * 16 + lm)
                        sacc[n][r] = -__builtin_inff();
        }
#pragma unroll
        for (int n = 0; n < 4; n++) {
            float e0 = exp2f(sacc[n][0]), e1 = exp2f(sacc[n][1]);
            float e2 = exp2f(sacc[n][2]), e3 = exp2f(sacc[n][3]);
            u32 lo, hi;
            asm("v_cvt_pk_bf16_f32 %0, %1, %2" : "=v"(lo) : "v"(e0), "v"(e1));
            asm("v_cvt_pk_bf16_f32 %0, %1, %2" : "=v"(hi) : "v"(e2), "v"(e3));
            const int pslot = (n * 4 + quad) ^ lm;     // 8B slot, conflict-free
            *(uint2*)(Pw + lm * 64 + pslot * 4) = (uint2){lo, hi};
        }
        // pf read: logical slots l0, l0+1 -> physical l^lm (b64 pair)
        short8 pf[2];
#pragma unroll
        for (int k4 = 0; k4 < 2; k4++) {
            const int l0 = k4 * 8 + quad * 2;
            uint2 a = *(const uint2*)(Pw + lm * 64 + ((l0 ^ lm) * 4));
            uint2 c = *(const uint2*)(Pw + lm * 64 + (((l0 + 1) ^ lm) * 4));
            union { short8 s; uint4 u; } m_;
            m_.u = (uint4){a.x, a.y, c.x, c.y};
            pf[k4] = m_.s;
        }
        // QK for NEXT tile (independent) -- hides the P LDS round-trip
        if (kt + 1 < nk) qk_tile(Ks[kb ^ 1]);
        // PV + row-sum
        __builtin_amdgcn_s_setprio(1);
#pragma unroll
        for (int n = 0; n < 4; n++) {
            const int r = n * 16 + lm;
            const u16* rowp = Vs[kb] + r * 64;
#pragma unroll
            for (int k4 = 0; k4 < 2; k4++) {
                short8 vf = *(const short8*)(rowp + (((k4 * 4 + quad) ^ (r & 7)) * 8));
                oacc[n] = __builtin_amdgcn_mfma_f32_16x16x32_bf16(pf[k4], vf, oacc[n], 0, 0, 0);
            }
        }
#pragma unroll
        for (int k4 = 0; k4 < 2; k4++)
            lacc = __builtin_amdgcn_mfma_f32_16x16x32_bf16(pf[k4], ones, lacc, 0, 0, 0);
        __builtin_amdgcn_s_setprio(0);

        if (kt + 1 < nk) __syncthreads();   // staged tiles landed; bufs safe
    }

    float inv[4];
#pragma unroll
    for (int r = 0; r < 4; r++) inv[r] = 1.0f / lacc[r];
#pragma unroll
    for (int n = 0; n < 4; n++)
#pragma unroll
        for (int r = 0; r < 4; r++) {
            const int qq = q0 + quad * 4 + r;
            Out[(size_t)(b * SEQ + qq) * HIDDEN + h * HD + n * 16 + lm] =
                f2bf(oacc[n][r] * inv[r]);
        }
}

// ---------------- launcher ------------------------------------------------
extern "C" void kernel_launch(void* const* d_in, const int* in_sizes, int n_in,
                              void* d_out, int out_size, void* d_ws, size_t ws_size,
                              hipStream_t stream) {
    const float* x  = (const float*)d_in[0];
    const float* Wq = (const float*)d_in[1];
    const float* bq = (const float*)d_in[2];
    const float* Wk = (const float*)d_in[3];
    const float* bk = (const float*)d_in[4];
    const float* Wv = (const float*)d_in[5];
    const float* bv = (const float*)d_in[6];
    const float* Wo = (const float*)d_in[7];
    const float* bo = (const float*)d_in[8];
    float* out = (float*)d_out;

    char* ws = (char*)d_ws;
    const size_t SZ_X = (size_t)4096 * 1024 * 2;   // 8 MB bf16
    const size_t SZ_W = (size_t)1024 * 1024 * 2;   // 2 MB bf16
    u16* xb    = (u16*)(ws);
    u16* wqb   = (u16*)(ws + SZ_X);
    u16* wkb   = (u16*)(ws + SZ_X + SZ_W);
    u16* wvb   = (u16*)(ws + SZ_X + 2 * SZ_W);
    u16* wob   = (u16*)(ws + SZ_X + 3 * SZ_W);
    u16* Qb    = (u16*)(ws + SZ_X + 4 * SZ_W);
    u16* Kb    = (u16*)(ws + 2 * SZ_X + 4 * SZ_W);
    u16* Vtb   = (u16*)(ws + 3 * SZ_X + 4 * SZ_W);
    u16* attnb = (u16*)(ws + 4 * SZ_X + 4 * SZ_W);

    cvt_all<<<4096, 256, 0, stream>>>(x, Wq, Wk, Wv, Wo, xb, wqb, wkb, wvb, wob);
    gemm_qkv<<<dim3(24, 32), 256, 0, stream>>>(xb, wqb, wkb, wvb, bq, bk, bv, Qb, Kb, Vtb);
    attn_kernel<<<BATCH * NH * (SEQ / 64), 256, 0, stream>>>(Qb, Kb, Vtb, attnb);
    gemm_out<<<dim3(8, 32), 512, 0, stream>>>(attnb, wob, bo, out);
}